// Round 1
// baseline (28949.371 us; speedup 1.0000x reference)
//
#include <hip/hip_runtime.h>

typedef unsigned short u16;
typedef __attribute__((ext_vector_type(8))) short s16x8;
typedef __attribute__((ext_vector_type(4))) short s16x4;
typedef __attribute__((ext_vector_type(4))) float f32x4;

#define TSTEPS 1024
#define PSTR   584                         // panel row stride in u16 (576 + 8 pad)
#define ZOFF   ((size_t)134217728)         // 256*1024*512
#define CZOFF  (ZOFF + 131072)             // + 256*512

// workspace layout (bytes)
#define CNT_OFF 0                          // 16 counters, 64B apart
#define HB_OFF  1024                       // h double buffer: 2*256*512 u16
#define WK_OFF  525312                     // packed weights 2048*576 u16
#define WX_OFF  2884608                    // x-weights 2048*2 f32
#define WB_OFF  2900992                    // bias 2048 f32
#define AW_OFF  2909184                    // alpha/hx weights 4*512 u16
#define AB_OFF  2913280                    // alpha/hx biases 4 f32

__device__ __forceinline__ float bf2f(u16 h) { union { unsigned u; float f; } c; c.u = ((unsigned)h) << 16; return c.f; }
__device__ __forceinline__ u16 f2bf(float f) { union { float f; unsigned u; } c; c.f = f; unsigned u = c.u; return (u16)((u + 0x7FFFu + ((u >> 16) & 1u)) >> 16); }
__device__ __forceinline__ float fsigm(float x) { return __builtin_amdgcn_rcpf(1.f + __builtin_amdgcn_exp2f(-1.44269504089f * x)); }
__device__ __forceinline__ float ftanh(float x) { float t = __builtin_amdgcn_exp2f(2.88539008178f * x); return 1.f - 2.f * __builtin_amdgcn_rcpf(t + 1.f); }
__device__ __forceinline__ float pick4(float a, float b, float c, float d, int m) {
  return (m == 0) ? a : (m == 1) ? b : (m == 2) ? c : d;
}

// ---------------- prep: pack weights (bf16, j-major gate interleave), zero counters ----------------
// n = j*4 + g  (j in [0,512) padded, g in {i,f,g,o}); K layout: [0..63]=inp cols (W_w[:,2:66]), [64..573]=U_w, [574..575]=0
__global__ void prep_pack(const float* __restrict__ W_w, const float* __restrict__ W_b,
                          const float* __restrict__ U_w, const float* __restrict__ alpha_w,
                          const float* __restrict__ alpha_b, const float* __restrict__ hx_w,
                          const float* __restrict__ hx_b,
                          u16* __restrict__ wk, float* __restrict__ wx, float* __restrict__ wb,
                          u16* __restrict__ aw, float* __restrict__ ab, unsigned* __restrict__ cnt)
{
  int n = blockIdx.x;
  int tid = threadIdx.x;
  if (n < 2048) {
    int j = n >> 2, g = n & 3;
    bool real = (j < 510);
    int row = g * 510 + j;
    for (int k = tid; k < 576; k += 64) {
      float v = 0.f;
      if (real) {
        if (k < 64) v = W_w[row * 66 + 2 + k];
        else { int kk = k - 64; v = (kk < 510) ? U_w[row * 510 + kk] : 0.f; }
      }
      wk[(size_t)n * 576 + k] = f2bf(v);
    }
    if (tid == 0) {
      wx[n * 2 + 0] = real ? W_w[row * 66 + 0] : 0.f;
      wx[n * 2 + 1] = real ? W_w[row * 66 + 1] : 0.f;
      wb[n] = real ? W_b[row] : 0.f;
    }
    if (n == 0 && tid < 16) cnt[tid * 16] = 0u;
  } else {
    int s = n - 2048; // 0,1: alpha rows; 2,3: hx rows
    for (int j = tid; j < 512; j += 64) {
      float v = 0.f;
      if (j < 510) v = (s < 2) ? alpha_w[s * 510 + j] : hx_w[(s - 2) * 510 + j];
      aw[s * 512 + j] = f2bf(v);
    }
    if (tid == 0) ab[s] = (s < 2) ? alpha_b[s] : hx_b[s - 2];
  }
}

// ---------------- prep: h(0) into h buffer 0 ----------------
__global__ void prep_h0(const float* __restrict__ z0, u16* __restrict__ hb0)
{
  int b = blockIdx.x;
  int j = threadIdx.x * 4;
#pragma unroll
  for (int e = 0; e < 4; ++e) {
    int jj = j + e;
    hb0[(size_t)b * 512 + jj] = (jj < 510) ? f2bf(z0[(size_t)b * 512 + 2 + jj]) : (u16)0;
  }
}

// ---------------- persistent LSTM kernel ----------------
// grid 256 = 16 groups x 16 WGs; group = bid&15 (co-XCD), w = bid>>4 owns gate cols [w*128, w*128+128)
extern "C" __global__ void __launch_bounds__(256, 1)
lstm_persist(const float* __restrict__ rnn, const float* __restrict__ tau,
             const float* __restrict__ z0, const float* __restrict__ cz0,
             const u16* __restrict__ wk, const float* __restrict__ wx, const float* __restrict__ wb,
             const u16* __restrict__ aw, const float* __restrict__ ab,
             u16* __restrict__ hbuf, unsigned* __restrict__ cnt,
             float* __restrict__ out)
{
  __shared__ u16  u_sh[16 * PSTR];
  __shared__ u16  aw_sh[4 * 512];
  __shared__ float ab_sh[4];
  __shared__ float xs_sh[16 * 2];

  const int tid = threadIdx.x;
  const int bid = blockIdx.x;
  const int grp = bid & 15;
  const int w   = bid >> 4;
  const int bb0 = grp * 16;
  const int v   = tid >> 6;
  const int l   = tid & 63;
  const int l15 = l & 15, l4 = l >> 4;
  const int n0  = w * 128 + v * 32;

  // --- startup ---
  {
    int r = tid >> 6, c8 = (tid & 63) * 8;
    *(s16x8*)&aw_sh[r * 512 + c8] = *(const s16x8*)&aw[r * 512 + c8];
    if (tid < 4) ab_sh[tid] = ab[tid];
  }
  // persistent B fragments: wave holds its 32 gate-cols x full K in VGPRs
  s16x8 bfr[36];
  {
    const u16* wb0 = wk + (size_t)(n0 + l15) * 576 + l4 * 8;
#pragma unroll
    for (int kf = 0; kf < 18; ++kf) {
      bfr[2 * kf + 0] = *(const s16x8*)(wb0 + kf * 32);
      bfr[2 * kf + 1] = *(const s16x8*)(wb0 + 16 * 576 + kf * 32);
    }
  }
  float wxf[2][2], wbf[2];
  {
    int nA = n0 + l15, nB = nA + 16;
    wxf[0][0] = wx[nA * 2]; wxf[0][1] = wx[nA * 2 + 1];
    wxf[1][0] = wx[nB * 2]; wxf[1][1] = wx[nB * 2 + 1];
    wbf[0] = wb[nA]; wbf[1] = wb[nB];
  }
  float cst[2][4];
#pragma unroll
  for (int nf = 0; nf < 2; ++nf) {
    int j = (n0 + nf * 16 + l15) >> 2;
#pragma unroll
    for (int r = 0; r < 4; ++r) {
      int b = bb0 + 4 * l4 + r;
      cst[nf][r] = (j < 510) ? cz0[(size_t)b * 512 + 2 + j] : 0.f;
    }
  }
  __syncthreads();

  const int prow = tid >> 4;
  const int jc   = tid & 15;
  unsigned* mycnt = cnt + grp * 16;

  for (int t = 0; t <= TSTEPS; ++t) {
    // ---- phase 0: stage h(t), inp(t); dots; x update ----
    const u16* hb = hbuf + (size_t)(t & 1) * (256 * 512) + (size_t)bb0 * 512;
    s16x8 hr0, hr1, hr2, hr3;
    {
      const s16x8* hp = (const s16x8*)hb + tid * 4;
      hr0 = hp[0]; hr1 = hp[1]; hr2 = hp[2]; hr3 = hp[3];
    }
    float4 inpv = make_float4(0.f, 0.f, 0.f, 0.f);
    if (t < TSTEPS) {
      const float* ip = rnn + (size_t)(bb0 + prow) * (TSTEPS * 64) + (size_t)t * 64 + jc * 4;
      inpv = *(const float4*)ip;
    }
    float s0 = 0.f, s1 = 0.f, s2 = 0.f, s3 = 0.f;
    {
#pragma unroll
      for (int q = 0; q < 4; ++q) {
        s16x8 h8 = (q == 0) ? hr0 : (q == 1) ? hr1 : (q == 2) ? hr2 : hr3;
        s16x8 a0 = *(const s16x8*)&aw_sh[0 * 512 + jc * 32 + q * 8];
        s16x8 a1 = *(const s16x8*)&aw_sh[1 * 512 + jc * 32 + q * 8];
        s16x8 a2 = *(const s16x8*)&aw_sh[2 * 512 + jc * 32 + q * 8];
        s16x8 a3 = *(const s16x8*)&aw_sh[3 * 512 + jc * 32 + q * 8];
#pragma unroll
        for (int e = 0; e < 8; ++e) {
          float hv = bf2f((u16)h8[e]);
          s0 += hv * bf2f((u16)a0[e]);
          s1 += hv * bf2f((u16)a1[e]);
          s2 += hv * bf2f((u16)a2[e]);
          s3 += hv * bf2f((u16)a3[e]);
        }
      }
#pragma unroll
      for (int m = 1; m <= 8; m <<= 1) {
        s0 += __shfl_xor(s0, m, 64);
        s1 += __shfl_xor(s1, m, 64);
        s2 += __shfl_xor(s2, m, 64);
        s3 += __shfl_xor(s3, m, 64);
      }
    }
    {
      u16* ur = &u_sh[prow * PSTR];
      *(s16x8*)(ur + 64 + jc * 32 +  0) = hr0;
      *(s16x8*)(ur + 64 + jc * 32 +  8) = hr1;
      *(s16x8*)(ur + 64 + jc * 32 + 16) = hr2;
      *(s16x8*)(ur + 64 + jc * 32 + 24) = hr3;
      if (t < TSTEPS) {
        s16x4 iv;
        iv[0] = (short)f2bf(inpv.x); iv[1] = (short)f2bf(inpv.y);
        iv[2] = (short)f2bf(inpv.z); iv[3] = (short)f2bf(inpv.w);
        *(s16x4*)(ur + jc * 4) = iv;
      }
    }
    if ((l & 15) == 0) {   // one lane per batch row: x recursion
      int row = prow;
      int b = bb0 + row;
      float xn0, xn1;
      if (t == 0) {
        xn0 = z0[(size_t)b * 512 + 0];
        xn1 = z0[(size_t)b * 512 + 1];
      } else {
        float x0p = xs_sh[row * 2 + 0], x1p = xs_sh[row * 2 + 1];
        float tv = tau[(size_t)b * TSTEPS + (t - 1)];
        float a0v = fsigm(s0 + ab_sh[0]);
        float a1v = fsigm(s1 + ab_sh[1]);
        float hx0 = s2 + ab_sh[2], hx1 = s3 + ab_sh[3];
        float xm0 = x0p + tv * (1.5f * x0p - 1.5f * x1p);
        float xm1 = x1p + tv * (0.6666666667f * x0p);
        xn0 = (1.f - a0v) * xm0 + a0v * hx0;
        xn1 = (1.f - a1v) * xm1 + a1v * hx1;
      }
      xs_sh[row * 2 + 0] = xn0; xs_sh[row * 2 + 1] = xn1;
      if (w == row && t >= 1) {
        float* ob = out + ((size_t)b * TSTEPS + (t - 1)) * 512;
        ob[0] = xn0; ob[1] = xn1;
        if (t == TSTEPS) {
          out[ZOFF + (size_t)b * 512 + 0] = xn0;
          out[ZOFF + (size_t)b * 512 + 1] = xn1;
          out[CZOFF + (size_t)b * 512 + 0] = cz0[(size_t)b * 512 + 0];
          out[CZOFF + (size_t)b * 512 + 1] = cz0[(size_t)b * 512 + 1];
        }
      }
    }
    __syncthreads();
    // ---- write output row (WG w owns batch row w of the group) ----
    if (t >= 1) {
      int j2 = tid * 2;
      if (j2 < 510) {
        unsigned hv2 = *(const unsigned*)&u_sh[w * PSTR + 64 + j2];
        float h0 = bf2f((u16)(hv2 & 0xFFFFu));
        float h1 = bf2f((u16)(hv2 >> 16));
        size_t ob = ((size_t)(bb0 + w) * TSTEPS + (t - 1)) * 512 + 2 + j2;
        out[ob] = h0; out[ob + 1] = h1;
        if (t == TSTEPS) {
          size_t zb = ZOFF + (size_t)(bb0 + w) * 512 + 2 + j2;
          out[zb] = h0; out[zb + 1] = h1;
        }
      }
    }
    if (t == TSTEPS) break;

    // ---- GEMM: M16 x N32(per wave) x K576, weights in registers ----
    f32x4 acc0 = {0.f, 0.f, 0.f, 0.f};
    f32x4 acc1 = {0.f, 0.f, 0.f, 0.f};
    {
      const u16* ap = &u_sh[l15 * PSTR + l4 * 8];
#pragma unroll
      for (int kf = 0; kf < 18; ++kf) {
        s16x8 a = *(const s16x8*)(ap + kf * 32);
        acc0 = __builtin_amdgcn_mfma_f32_16x16x32_bf16(a, bfr[2 * kf + 0], acc0, 0, 0, 0);
        acc1 = __builtin_amdgcn_mfma_f32_16x16x32_bf16(a, bfr[2 * kf + 1], acc1, 0, 0, 0);
      }
    }
    // ---- epilogue: bias + rank-2 x-term, gate combine, LSTM cell, h store ----
    u16* hout = hbuf + (size_t)((t + 1) & 1) * (256 * 512);
    float xr[4][2];
#pragma unroll
    for (int r = 0; r < 4; ++r) {
      xr[r][0] = xs_sh[(4 * l4 + r) * 2 + 0];
      xr[r][1] = xs_sh[(4 * l4 + r) * 2 + 1];
    }
    const int g = l & 3;
#pragma unroll
    for (int nf = 0; nf < 2; ++nf) {
      int nn = n0 + nf * 16 + l15;
      int j = nn >> 2;
      f32x4 av = nf ? acc1 : acc0;
#pragma unroll
      for (int r = 0; r < 4; ++r) {
        float pre = av[r] + wbf[nf] + xr[r][0] * wxf[nf][0] + xr[r][1] * wxf[nf][1];
        float vA = pre;
        float vB = __shfl_xor(vA, 1, 64);
        float vC = __shfl_xor(vA, 2, 64);
        float vD = __shfl_xor(vB, 2, 64);
        float iv = pick4(vA, vB, vC, vD, g);
        float fv = pick4(vA, vB, vC, vD, g ^ 1);
        float gv = pick4(vA, vB, vC, vD, g ^ 2);
        float ov = pick4(vA, vB, vC, vD, g ^ 3);
        float si = fsigm(iv), sf = fsigm(fv), tg = ftanh(gv), so = fsigm(ov);
        float cn = sf * cst[nf][r] + si * tg;
        cst[nf][r] = cn;
        float hn = so * ftanh(cn);
        if (g == r) {
          hout[(size_t)(bb0 + 4 * l4 + r) * 512 + j] = f2bf(hn);
        }
      }
    }
    // ---- group barrier (16 WGs, monotonic counter) ----
    __threadfence();
    __syncthreads();
    if (tid == 0) {
      __hip_atomic_fetch_add(mycnt, 1u, __ATOMIC_RELEASE, __HIP_MEMORY_SCOPE_AGENT);
      unsigned tgt = 16u * (unsigned)(t + 1);
      while (__hip_atomic_load(mycnt, __ATOMIC_RELAXED, __HIP_MEMORY_SCOPE_AGENT) < tgt) {
        __builtin_amdgcn_s_sleep(2);
      }
      (void)__hip_atomic_load(mycnt, __ATOMIC_ACQUIRE, __HIP_MEMORY_SCOPE_AGENT);
    }
    __syncthreads();
  }

  // ---- final cell state: cz_fin[:, 2:512] = c(T) ----
#pragma unroll
  for (int nf = 0; nf < 2; ++nf) {
    int j = (n0 + nf * 16 + l15) >> 2;
    if (j < 510) {
#pragma unroll
      for (int r = 0; r < 4; ++r) {
        if ((l & 3) == r) {
          out[CZOFF + (size_t)(bb0 + 4 * l4 + r) * 512 + 2 + j] = cst[nf][r];
        }
      }
    }
  }
}

extern "C" void kernel_launch(void* const* d_in, const int* in_sizes, int n_in,
                              void* d_out, int out_size, void* d_ws, size_t ws_size,
                              hipStream_t stream) {
  const float* rnn     = (const float*)d_in[0];
  const float* tau     = (const float*)d_in[1];
  const float* z0      = (const float*)d_in[2];
  const float* cz0     = (const float*)d_in[3];
  const float* W_w     = (const float*)d_in[4];
  const float* W_b     = (const float*)d_in[5];
  const float* U_w     = (const float*)d_in[6];
  const float* alpha_w = (const float*)d_in[7];
  const float* alpha_b = (const float*)d_in[8];
  const float* hx_w    = (const float*)d_in[9];
  const float* hx_b    = (const float*)d_in[10];

  char* ws = (char*)d_ws;
  unsigned* cnt = (unsigned*)(ws + CNT_OFF);
  u16*      hb  = (u16*)(ws + HB_OFF);
  u16*      wk  = (u16*)(ws + WK_OFF);
  float*    wx  = (float*)(ws + WX_OFF);
  float*    wbv = (float*)(ws + WB_OFF);
  u16*      awv = (u16*)(ws + AW_OFF);
  float*    abv = (float*)(ws + AB_OFF);

  hipLaunchKernelGGL(prep_pack, dim3(2052), dim3(64), 0, stream,
                     W_w, W_b, U_w, alpha_w, alpha_b, hx_w, hx_b, wk, wx, wbv, awv, abv, cnt);
  hipLaunchKernelGGL(prep_h0, dim3(256), dim3(128), 0, stream, z0, hb);
  hipLaunchKernelGGL(lstm_persist, dim3(256), dim3(256), 0, stream,
                     rnn, tau, z0, cz0, wk, wx, wbv, awv, abv, hb, cnt, (float*)d_out);
}

// Round 3
// 8139.508 us; speedup vs baseline: 3.5566x; 3.5566x over previous
//
#include <hip/hip_runtime.h>

typedef unsigned short u16;
typedef unsigned int u32;
typedef unsigned long long u64;
typedef __attribute__((ext_vector_type(8))) short s16x8;
typedef __attribute__((ext_vector_type(4))) short s16x4;
typedef __attribute__((ext_vector_type(4))) float f32x4;

#define TSTEPS 1024
#define PSTR   584                         // panel row stride in u16 (576 + 8 pad)
#define ZOFF   ((size_t)134217728)         // 256*1024*512
#define CZOFF  (ZOFF + 131072)             // + 256*512

// workspace layout (bytes)
#define CNT_OFF 0                          // 16 counters, 64B apart
#define HB_OFF  1024                       // h double buffer: 2*256*512 u16
#define WK_OFF  525312                     // packed weights 2048*576 u16
#define WX_OFF  2884608                    // x-weights 2048*2 f32
#define WB_OFF  2900992                    // bias 2048 f32
#define AW_OFF  2909184                    // alpha/hx weights 4*512 u16
#define AB_OFF  2913280                    // alpha/hx biases 4 f32

__device__ __forceinline__ float bf2f(u16 h) { union { unsigned u; float f; } c; c.u = ((unsigned)h) << 16; return c.f; }
__device__ __forceinline__ u16 f2bf(float f) { union { float f; unsigned u; } c; c.f = f; unsigned u = c.u; return (u16)((u + 0x7FFFu + ((u >> 16) & 1u)) >> 16); }
__device__ __forceinline__ float fsigm(float x) { return __builtin_amdgcn_rcpf(1.f + __builtin_amdgcn_exp2f(-1.44269504089f * x)); }
__device__ __forceinline__ float ftanh(float x) { float t = __builtin_amdgcn_exp2f(2.88539008178f * x); return 1.f - 2.f * __builtin_amdgcn_rcpf(t + 1.f); }
__device__ __forceinline__ float pick4(float a, float b, float c, float d, int m) {
  return (m == 0) ? a : (m == 1) ? b : (m == 2) ? c : d;
}
#define NTS(p, v) __builtin_nontemporal_store((v), (p))

// ---------------- prep: pack weights (bf16, j-major gate interleave), zero counters ----------------
// n = j*4 + g  (j in [0,512) padded, g in {i,f,g,o}); K layout: [0..63]=inp cols (W_w[:,2:66]), [64..573]=U_w, [574..575]=0
__global__ void prep_pack(const float* __restrict__ W_w, const float* __restrict__ W_b,
                          const float* __restrict__ U_w, const float* __restrict__ alpha_w,
                          const float* __restrict__ alpha_b, const float* __restrict__ hx_w,
                          const float* __restrict__ hx_b,
                          u16* __restrict__ wk, float* __restrict__ wx, float* __restrict__ wb,
                          u16* __restrict__ aw, float* __restrict__ ab, unsigned* __restrict__ cnt)
{
  int n = blockIdx.x;
  int tid = threadIdx.x;
  if (n < 2048) {
    int j = n >> 2, g = n & 3;
    bool real = (j < 510);
    int row = g * 510 + j;
    for (int k = tid; k < 576; k += 64) {
      float v = 0.f;
      if (real) {
        if (k < 64) v = W_w[row * 66 + 2 + k];
        else { int kk = k - 64; v = (kk < 510) ? U_w[row * 510 + kk] : 0.f; }
      }
      wk[(size_t)n * 576 + k] = f2bf(v);
    }
    if (tid == 0) {
      wx[n * 2 + 0] = real ? W_w[row * 66 + 0] : 0.f;
      wx[n * 2 + 1] = real ? W_w[row * 66 + 1] : 0.f;
      wb[n] = real ? W_b[row] : 0.f;
    }
    // atomic zero -> value is unambiguously at the device coherence point for the
    // persistent kernel's MALL-executed RMWs (replay-safe).
    if (n == 0 && tid < 16)
      __hip_atomic_store(&cnt[tid * 16], 0u, __ATOMIC_RELAXED, __HIP_MEMORY_SCOPE_AGENT);
  } else {
    int s = n - 2048; // 0,1: alpha rows; 2,3: hx rows
    for (int j = tid; j < 512; j += 64) {
      float v = 0.f;
      if (j < 510) v = (s < 2) ? alpha_w[s * 510 + j] : hx_w[(s - 2) * 510 + j];
      aw[s * 512 + j] = f2bf(v);
    }
    if (tid == 0) ab[s] = (s < 2) ? alpha_b[s] : hx_b[s - 2];
  }
}

// ---------------- prep: h(0) into h buffer 0 ----------------
__global__ void prep_h0(const float* __restrict__ z0, u16* __restrict__ hb0)
{
  int b = blockIdx.x;
  int j = threadIdx.x * 4;
#pragma unroll
  for (int e = 0; e < 4; ++e) {
    int jj = j + e;
    hb0[(size_t)b * 512 + jj] = (jj < 510) ? f2bf(z0[(size_t)b * 512 + 2 + jj]) : (u16)0;
  }
}

// ---------------- persistent LSTM kernel ----------------
// grid 256 = 16 groups x 16 WGs; group = bid&15, w = bid>>4 owns gate cols [w*128, w*128+128)
// h exchange: relaxed sc0/sc1 atomic stores/loads (point-to-point at MALL, cache-bypassing).
// Barrier: producer fetch_add with RELEASE (waitcnt+wbl2 -> h data at MALL before signal
// visible); consumer polls RELAXED (its h loads bypass caches; s_barrier blocks hoisting).
// NO acquire/threadfence anywhere: buffer_inv L2-invalidate storms were round 1's 29 ms.
extern "C" __global__ void __launch_bounds__(256, 1)
lstm_persist(const float* __restrict__ rnn, const float* __restrict__ tau,
             const float* __restrict__ z0, const float* __restrict__ cz0,
             const u16* __restrict__ wk, const float* __restrict__ wx, const float* __restrict__ wb,
             const u16* __restrict__ aw, const float* __restrict__ ab,
             u16* __restrict__ hbuf, unsigned* __restrict__ cnt,
             float* __restrict__ out)
{
  __shared__ u16  u_sh[16 * PSTR];
  __shared__ u16  aw_sh[4 * 512];
  __shared__ float ab_sh[4];
  __shared__ float xs_sh[16 * 2];

  const int tid = threadIdx.x;
  const int bid = blockIdx.x;
  const int grp = bid & 15;
  const int w   = bid >> 4;
  const int bb0 = grp * 16;
  const int v   = tid >> 6;
  const int l   = tid & 63;
  const int l15 = l & 15, l4 = l >> 4;
  const int n0  = w * 128 + v * 32;

  // --- startup ---
  {
    int r = tid >> 6, c8 = (tid & 63) * 8;
    *(s16x8*)&aw_sh[r * 512 + c8] = *(const s16x8*)&aw[r * 512 + c8];
    if (tid < 4) ab_sh[tid] = ab[tid];
  }
  // persistent B fragments: wave holds its 32 gate-cols x full K in VGPRs
  s16x8 bfr[36];
  {
    const u16* wb0 = wk + (size_t)(n0 + l15) * 576 + l4 * 8;
#pragma unroll
    for (int kf = 0; kf < 18; ++kf) {
      bfr[2 * kf + 0] = *(const s16x8*)(wb0 + kf * 32);
      bfr[2 * kf + 1] = *(const s16x8*)(wb0 + 16 * 576 + kf * 32);
    }
  }
  float wxf[2][2], wbf[2];
  {
    int nA = n0 + l15, nB = nA + 16;
    wxf[0][0] = wx[nA * 2]; wxf[0][1] = wx[nA * 2 + 1];
    wxf[1][0] = wx[nB * 2]; wxf[1][1] = wx[nB * 2 + 1];
    wbf[0] = wb[nA]; wbf[1] = wb[nB];
  }
  float cst[2][4];
#pragma unroll
  for (int nf = 0; nf < 2; ++nf) {
    int j = (n0 + nf * 16 + l15) >> 2;
#pragma unroll
    for (int r = 0; r < 4; ++r) {
      int b = bb0 + 4 * l4 + r;
      cst[nf][r] = (j < 510) ? cz0[(size_t)b * 512 + 2 + j] : 0.f;
    }
  }
  __syncthreads();

  const int prow = tid >> 4;
  const int jc   = tid & 15;
  unsigned* mycnt = cnt + grp * 16;

  for (int t = 0; t <= TSTEPS; ++t) {
    // ---- phase 0: load h(t) via device-coherent relaxed atomic loads ----
    u16* hb = hbuf + (size_t)(t & 1) * (256 * 512) + (size_t)bb0 * 512;
    u64 q0, q1, q2, q3, q4, q5, q6, q7;
    {
      u64* hp = (u64*)hb + (size_t)tid * 8;
      q0 = __hip_atomic_load(hp + 0, __ATOMIC_RELAXED, __HIP_MEMORY_SCOPE_AGENT);
      q1 = __hip_atomic_load(hp + 1, __ATOMIC_RELAXED, __HIP_MEMORY_SCOPE_AGENT);
      q2 = __hip_atomic_load(hp + 2, __ATOMIC_RELAXED, __HIP_MEMORY_SCOPE_AGENT);
      q3 = __hip_atomic_load(hp + 3, __ATOMIC_RELAXED, __HIP_MEMORY_SCOPE_AGENT);
      q4 = __hip_atomic_load(hp + 4, __ATOMIC_RELAXED, __HIP_MEMORY_SCOPE_AGENT);
      q5 = __hip_atomic_load(hp + 5, __ATOMIC_RELAXED, __HIP_MEMORY_SCOPE_AGENT);
      q6 = __hip_atomic_load(hp + 6, __ATOMIC_RELAXED, __HIP_MEMORY_SCOPE_AGENT);
      q7 = __hip_atomic_load(hp + 7, __ATOMIC_RELAXED, __HIP_MEMORY_SCOPE_AGENT);
    }
    s16x8 hr0, hr1, hr2, hr3;
    { u64 t2[2]; t2[0] = q0; t2[1] = q1; __builtin_memcpy(&hr0, t2, 16); }
    { u64 t2[2]; t2[0] = q2; t2[1] = q3; __builtin_memcpy(&hr1, t2, 16); }
    { u64 t2[2]; t2[0] = q4; t2[1] = q5; __builtin_memcpy(&hr2, t2, 16); }
    { u64 t2[2]; t2[0] = q6; t2[1] = q7; __builtin_memcpy(&hr3, t2, 16); }

    float4 inpv = make_float4(0.f, 0.f, 0.f, 0.f);
    if (t < TSTEPS) {
      const float* ip = rnn + (size_t)(bb0 + prow) * (TSTEPS * 64) + (size_t)t * 64 + jc * 4;
      inpv = *(const float4*)ip;
    }
    float s0 = 0.f, s1 = 0.f, s2 = 0.f, s3 = 0.f;
    {
#pragma unroll
      for (int q = 0; q < 4; ++q) {
        s16x8 h8 = (q == 0) ? hr0 : (q == 1) ? hr1 : (q == 2) ? hr2 : hr3;
        s16x8 a0 = *(const s16x8*)&aw_sh[0 * 512 + jc * 32 + q * 8];
        s16x8 a1 = *(const s16x8*)&aw_sh[1 * 512 + jc * 32 + q * 8];
        s16x8 a2 = *(const s16x8*)&aw_sh[2 * 512 + jc * 32 + q * 8];
        s16x8 a3 = *(const s16x8*)&aw_sh[3 * 512 + jc * 32 + q * 8];
#pragma unroll
        for (int e = 0; e < 8; ++e) {
          float hv = bf2f((u16)h8[e]);
          s0 += hv * bf2f((u16)a0[e]);
          s1 += hv * bf2f((u16)a1[e]);
          s2 += hv * bf2f((u16)a2[e]);
          s3 += hv * bf2f((u16)a3[e]);
        }
      }
#pragma unroll
      for (int m = 1; m <= 8; m <<= 1) {
        s0 += __shfl_xor(s0, m, 64);
        s1 += __shfl_xor(s1, m, 64);
        s2 += __shfl_xor(s2, m, 64);
        s3 += __shfl_xor(s3, m, 64);
      }
    }
    {
      u16* ur = &u_sh[prow * PSTR];
      *(s16x8*)(ur + 64 + jc * 32 +  0) = hr0;
      *(s16x8*)(ur + 64 + jc * 32 +  8) = hr1;
      *(s16x8*)(ur + 64 + jc * 32 + 16) = hr2;
      *(s16x8*)(ur + 64 + jc * 32 + 24) = hr3;
      if (t < TSTEPS) {
        s16x4 iv;
        iv[0] = (short)f2bf(inpv.x); iv[1] = (short)f2bf(inpv.y);
        iv[2] = (short)f2bf(inpv.z); iv[3] = (short)f2bf(inpv.w);
        *(s16x4*)(ur + jc * 4) = iv;
      }
    }
    if ((l & 15) == 0) {   // one lane per batch row: x recursion
      int row = prow;
      int b = bb0 + row;
      float xn0, xn1;
      if (t == 0) {
        xn0 = z0[(size_t)b * 512 + 0];
        xn1 = z0[(size_t)b * 512 + 1];
      } else {
        float x0p = xs_sh[row * 2 + 0], x1p = xs_sh[row * 2 + 1];
        float tv = tau[(size_t)b * TSTEPS + (t - 1)];
        float a0v = fsigm(s0 + ab_sh[0]);
        float a1v = fsigm(s1 + ab_sh[1]);
        float hx0 = s2 + ab_sh[2], hx1 = s3 + ab_sh[3];
        float xm0 = x0p + tv * (1.5f * x0p - 1.5f * x1p);
        float xm1 = x1p + tv * (0.6666666667f * x0p);
        xn0 = (1.f - a0v) * xm0 + a0v * hx0;
        xn1 = (1.f - a1v) * xm1 + a1v * hx1;
      }
      xs_sh[row * 2 + 0] = xn0; xs_sh[row * 2 + 1] = xn1;
      if (w == row && t >= 1) {
        float* ob = out + ((size_t)b * TSTEPS + (t - 1)) * 512;
        NTS(ob + 0, xn0); NTS(ob + 1, xn1);
        if (t == TSTEPS) {
          NTS(&out[ZOFF + (size_t)b * 512 + 0], xn0);
          NTS(&out[ZOFF + (size_t)b * 512 + 1], xn1);
          NTS(&out[CZOFF + (size_t)b * 512 + 0], cz0[(size_t)b * 512 + 0]);
          NTS(&out[CZOFF + (size_t)b * 512 + 1], cz0[(size_t)b * 512 + 1]);
        }
      }
    }
    __syncthreads();
    // ---- write output row (WG w owns batch row w of the group) ----
    if (t >= 1) {
      int j2 = tid * 2;
      if (j2 < 510) {
        unsigned hv2 = *(const unsigned*)&u_sh[w * PSTR + 64 + j2];
        float h0 = bf2f((u16)(hv2 & 0xFFFFu));
        float h1 = bf2f((u16)(hv2 >> 16));
        size_t ob = ((size_t)(bb0 + w) * TSTEPS + (t - 1)) * 512 + 2 + j2;
        NTS(&out[ob], h0); NTS(&out[ob + 1], h1);
        if (t == TSTEPS) {
          size_t zb = ZOFF + (size_t)(bb0 + w) * 512 + 2 + j2;
          NTS(&out[zb], h0); NTS(&out[zb + 1], h1);
        }
      }
    }
    if (t == TSTEPS) break;

    // ---- GEMM: M16 x N32(per wave) x K576, weights in registers ----
    f32x4 acc0 = {0.f, 0.f, 0.f, 0.f};
    f32x4 acc1 = {0.f, 0.f, 0.f, 0.f};
    {
      const u16* ap = &u_sh[l15 * PSTR + l4 * 8];
#pragma unroll
      for (int kf = 0; kf < 18; ++kf) {
        s16x8 a = *(const s16x8*)(ap + kf * 32);
        acc0 = __builtin_amdgcn_mfma_f32_16x16x32_bf16(a, bfr[2 * kf + 0], acc0, 0, 0, 0);
        acc1 = __builtin_amdgcn_mfma_f32_16x16x32_bf16(a, bfr[2 * kf + 1], acc1, 0, 0, 0);
      }
    }
    // ---- epilogue: bias + rank-2 x-term, gate combine, LSTM cell, h store ----
    u16* hout = hbuf + (size_t)((t + 1) & 1) * (256 * 512);
    float xr[4][2];
#pragma unroll
    for (int r = 0; r < 4; ++r) {
      xr[r][0] = xs_sh[(4 * l4 + r) * 2 + 0];
      xr[r][1] = xs_sh[(4 * l4 + r) * 2 + 1];
    }
    const int g = l & 3;
    float myh0 = 0.f, myh1 = 0.f;
#pragma unroll
    for (int nf = 0; nf < 2; ++nf) {
      f32x4 av = nf ? acc1 : acc0;
#pragma unroll
      for (int r = 0; r < 4; ++r) {
        float pre = av[r] + wbf[nf] + xr[r][0] * wxf[nf][0] + xr[r][1] * wxf[nf][1];
        float vA = pre;
        float vB = __shfl_xor(vA, 1, 64);
        float vC = __shfl_xor(vA, 2, 64);
        float vD = __shfl_xor(vB, 2, 64);
        float iv = pick4(vA, vB, vC, vD, g);
        float fv = pick4(vA, vB, vC, vD, g ^ 1);
        float gv = pick4(vA, vB, vC, vD, g ^ 2);
        float ov = pick4(vA, vB, vC, vD, g ^ 3);
        float si = fsigm(iv), sf = fsigm(fv), tg = ftanh(gv), so = fsigm(ov);
        float cn = sf * cst[nf][r] + si * tg;
        cst[nf][r] = cn;
        float hn = so * ftanh(cn);
        if (g == r) { if (nf == 0) myh0 = hn; else myh1 = hn; }
      }
    }
    // pair adjacent columns across lanes (l15 ^ 4) -> aligned u32 device-coherent stores
    {
      int row = 4 * l4 + g;
      u32 mine = (u32)f2bf(myh0) | ((u32)f2bf(myh1) << 16);
      u32 oth = (u32)__shfl_xor((int)mine, 4, 64);
      if (((l15 >> 2) & 1) == 0) {
        int j0 = (n0 >> 2) + (l15 >> 2);     // even column index
        u32 v0 = (mine & 0xFFFFu) | ((oth & 0xFFFFu) << 16);   // cols j0, j0+1   (nf=0)
        u32 v1 = (mine >> 16) | (oth & 0xFFFF0000u);           // cols j0+4, j0+5 (nf=1)
        u32* hp = (u32*)(hout + (size_t)(bb0 + row) * 512);
        __hip_atomic_store(hp + (j0 >> 1), v0, __ATOMIC_RELAXED, __HIP_MEMORY_SCOPE_AGENT);
        __hip_atomic_store(hp + (j0 >> 1) + 2, v1, __ATOMIC_RELAXED, __HIP_MEMORY_SCOPE_AGENT);
      }
    }
    // ---- group barrier ----
    // RELEASE on the add: waitcnt vmcnt(0) + L2 writeback BEFORE the MALL counter bump,
    // so in-flight write-through h stores are at the coherence point when peers see the
    // count. (Round 2's relaxed add raced exactly here.) out is nt-stored -> L2 is clean
    // -> the per-step wbl2 is cheap.
    __syncthreads();
    if (tid == 0) {
      __hip_atomic_fetch_add(mycnt, 1u, __ATOMIC_RELEASE, __HIP_MEMORY_SCOPE_AGENT);
      unsigned tgt = 16u * (unsigned)(t + 1);
      while (__hip_atomic_load(mycnt, __ATOMIC_RELAXED, __HIP_MEMORY_SCOPE_AGENT) < tgt) {
        __builtin_amdgcn_s_sleep(1);
      }
    }
    __syncthreads();
  }

  // ---- final cell state: cz_fin[:, 2:512] = c(T) ----
#pragma unroll
  for (int nf = 0; nf < 2; ++nf) {
    int j = (n0 + nf * 16 + l15) >> 2;
    if (j < 510) {
#pragma unroll
      for (int r = 0; r < 4; ++r) {
        if ((l & 3) == r) {
          NTS(&out[CZOFF + (size_t)(bb0 + 4 * l4 + r) * 512 + 2 + j], cst[nf][r]);
        }
      }
    }
  }
}

extern "C" void kernel_launch(void* const* d_in, const int* in_sizes, int n_in,
                              void* d_out, int out_size, void* d_ws, size_t ws_size,
                              hipStream_t stream) {
  const float* rnn     = (const float*)d_in[0];
  const float* tau     = (const float*)d_in[1];
  const float* z0      = (const float*)d_in[2];
  const float* cz0     = (const float*)d_in[3];
  const float* W_w     = (const float*)d_in[4];
  const float* W_b     = (const float*)d_in[5];
  const float* U_w     = (const float*)d_in[6];
  const float* alpha_w = (const float*)d_in[7];
  const float* alpha_b = (const float*)d_in[8];
  const float* hx_w    = (const float*)d_in[9];
  const float* hx_b    = (const float*)d_in[10];

  char* ws = (char*)d_ws;
  unsigned* cnt = (unsigned*)(ws + CNT_OFF);
  u16*      hb  = (u16*)(ws + HB_OFF);
  u16*      wk  = (u16*)(ws + WK_OFF);
  float*    wx  = (float*)(ws + WX_OFF);
  float*    wbv = (float*)(ws + WB_OFF);
  u16*      awv = (u16*)(ws + AW_OFF);
  float*    abv = (float*)(ws + AB_OFF);

  hipLaunchKernelGGL(prep_pack, dim3(2052), dim3(64), 0, stream,
                     W_w, W_b, U_w, alpha_w, alpha_b, hx_w, hx_b, wk, wx, wbv, awv, abv, cnt);
  hipLaunchKernelGGL(prep_h0, dim3(256), dim3(128), 0, stream, z0, hb);
  hipLaunchKernelGGL(lstm_persist, dim3(256), dim3(256), 0, stream,
                     rnn, tau, z0, cz0, wk, wx, wbv, awv, abv, hb, cnt, (float*)d_out);
}

// Round 4
// 6461.659 us; speedup vs baseline: 4.4802x; 1.2597x over previous
//
#include <hip/hip_runtime.h>

typedef unsigned short u16;
typedef unsigned int u32;
typedef unsigned long long u64;
typedef __attribute__((ext_vector_type(8))) short s16x8;
typedef __attribute__((ext_vector_type(4))) short s16x4;
typedef __attribute__((ext_vector_type(4))) float f32x4;

#define TSTEPS 1024
#define PSTR   584                         // panel row stride in u16 (576 + 8 pad)
#define ZOFF   ((size_t)134217728)         // 256*1024*512
#define CZOFF  (ZOFF + 131072)             // + 256*512

// workspace layout (bytes)
#define CNT_OFF 0                          // 16 counters, 64B apart
#define HB_OFF  1024                       // h double buffer: 2*256*512 u16
#define WK_OFF  525312                     // packed weights 2048*576 u16
#define WX_OFF  2884608                    // x-weights 2048*2 f32
#define WB_OFF  2900992                    // bias 2048 f32
#define AW_OFF  2909184                    // alpha/hx weights 4*512 u16
#define AB_OFF  2913280                    // alpha/hx biases 4 f32

__device__ __forceinline__ float bf2f(u16 h) { union { unsigned u; float f; } c; c.u = ((unsigned)h) << 16; return c.f; }
__device__ __forceinline__ u16 f2bf(float f) { union { float f; unsigned u; } c; c.f = f; unsigned u = c.u; return (u16)((u + 0x7FFFu + ((u >> 16) & 1u)) >> 16); }
__device__ __forceinline__ float fsigm(float x) { return __builtin_amdgcn_rcpf(1.f + __builtin_amdgcn_exp2f(-1.44269504089f * x)); }
__device__ __forceinline__ float ftanh(float x) { float t = __builtin_amdgcn_exp2f(2.88539008178f * x); return 1.f - 2.f * __builtin_amdgcn_rcpf(t + 1.f); }
__device__ __forceinline__ float pick4(float a, float b, float c, float d, int m) {
  return (m == 0) ? a : (m == 1) ? b : (m == 2) ? c : d;
}
#define NTS(p, v) __builtin_nontemporal_store((v), (p))

// ---------------- prep: pack weights (bf16, j-major gate interleave), zero counters ----------------
// n = j*4 + g  (j in [0,512) padded, g in {i,f,g,o}); K layout: [0..63]=inp cols (W_w[:,2:66]), [64..573]=U_w, [574..575]=0
__global__ void prep_pack(const float* __restrict__ W_w, const float* __restrict__ W_b,
                          const float* __restrict__ U_w, const float* __restrict__ alpha_w,
                          const float* __restrict__ alpha_b, const float* __restrict__ hx_w,
                          const float* __restrict__ hx_b,
                          u16* __restrict__ wk, float* __restrict__ wx, float* __restrict__ wb,
                          u16* __restrict__ aw, float* __restrict__ ab, unsigned* __restrict__ cnt)
{
  int n = blockIdx.x;
  int tid = threadIdx.x;
  if (n < 2048) {
    int j = n >> 2, g = n & 3;
    bool real = (j < 510);
    int row = g * 510 + j;
    for (int k = tid; k < 576; k += 64) {
      float v = 0.f;
      if (real) {
        if (k < 64) v = W_w[row * 66 + 2 + k];
        else { int kk = k - 64; v = (kk < 510) ? U_w[row * 510 + kk] : 0.f; }
      }
      wk[(size_t)n * 576 + k] = f2bf(v);
    }
    if (tid == 0) {
      wx[n * 2 + 0] = real ? W_w[row * 66 + 0] : 0.f;
      wx[n * 2 + 1] = real ? W_w[row * 66 + 1] : 0.f;
      wb[n] = real ? W_b[row] : 0.f;
    }
    // atomic zero -> value is unambiguously at the device coherence point for the
    // persistent kernel's MALL-executed RMWs (replay-safe).
    if (n == 0 && tid < 16)
      __hip_atomic_store(&cnt[tid * 16], 0u, __ATOMIC_RELAXED, __HIP_MEMORY_SCOPE_AGENT);
  } else {
    int s = n - 2048; // 0,1: alpha rows; 2,3: hx rows
    for (int j = tid; j < 512; j += 64) {
      float v = 0.f;
      if (j < 510) v = (s < 2) ? alpha_w[s * 510 + j] : hx_w[(s - 2) * 510 + j];
      aw[s * 512 + j] = f2bf(v);
    }
    if (tid == 0) ab[s] = (s < 2) ? alpha_b[s] : hx_b[s - 2];
  }
}

// ---------------- prep: h(0) into h buffer 0 ----------------
__global__ void prep_h0(const float* __restrict__ z0, u16* __restrict__ hb0)
{
  int b = blockIdx.x;
  int j = threadIdx.x * 4;
#pragma unroll
  for (int e = 0; e < 4; ++e) {
    int jj = j + e;
    hb0[(size_t)b * 512 + jj] = (jj < 510) ? f2bf(z0[(size_t)b * 512 + 2 + jj]) : (u16)0;
  }
}

// ---------------- persistent LSTM kernel ----------------
// grid 256 = 16 groups x 16 WGs; group = bid&15, w = bid>>4 owns gate cols [w*128, w*128+128)
// h exchange: relaxed sc0/sc1 atomic stores/loads (point-to-point at MALL, cache-bypassing).
// Barrier: RELAXED fetch_add + RELAXED poll. Safety argument: ALL cross-WG-communicated
// stores are themselves agent-scope (sc0/sc1, write-through); vmcnt ack for such stores
// = accepted at the coherence point, and every wave drains vmcnt(0) at the __syncthreads
// before tid0 signals. The RELEASE's buffer_wbl2 (L2 dirty-line flush, round 3) only
// exists to cover PLAIN stores -- we have none that peers read -> pure overhead, dropped.
// cnt zeroing in prep is atomic (round-2 replay race was cnt poisoning, not h visibility).
extern "C" __global__ void __launch_bounds__(256, 1)
lstm_persist(const float* __restrict__ rnn, const float* __restrict__ tau,
             const float* __restrict__ z0, const float* __restrict__ cz0,
             const u16* __restrict__ wk, const float* __restrict__ wx, const float* __restrict__ wb,
             const u16* __restrict__ aw, const float* __restrict__ ab,
             u16* __restrict__ hbuf, unsigned* __restrict__ cnt,
             float* __restrict__ out)
{
  __shared__ u16  u_sh[16 * PSTR];
  __shared__ u16  aw_sh[4 * 512];
  __shared__ float ab_sh[4];
  __shared__ float xs_sh[16 * 2];

  const int tid = threadIdx.x;
  const int bid = blockIdx.x;
  const int grp = bid & 15;
  const int w   = bid >> 4;
  const int bb0 = grp * 16;
  const int v   = tid >> 6;
  const int l   = tid & 63;
  const int l15 = l & 15, l4 = l >> 4;
  const int n0  = w * 128 + v * 32;

  // --- startup ---
  {
    int r = tid >> 6, c8 = (tid & 63) * 8;
    *(s16x8*)&aw_sh[r * 512 + c8] = *(const s16x8*)&aw[r * 512 + c8];
    if (tid < 4) ab_sh[tid] = ab[tid];
  }
  // persistent B fragments: wave holds its 32 gate-cols x full K in VGPRs
  s16x8 bfr[36];
  {
    const u16* wb0 = wk + (size_t)(n0 + l15) * 576 + l4 * 8;
#pragma unroll
    for (int kf = 0; kf < 18; ++kf) {
      bfr[2 * kf + 0] = *(const s16x8*)(wb0 + kf * 32);
      bfr[2 * kf + 1] = *(const s16x8*)(wb0 + 16 * 576 + kf * 32);
    }
  }
  float wxf[2][2], wbf[2];
  {
    int nA = n0 + l15, nB = nA + 16;
    wxf[0][0] = wx[nA * 2]; wxf[0][1] = wx[nA * 2 + 1];
    wxf[1][0] = wx[nB * 2]; wxf[1][1] = wx[nB * 2 + 1];
    wbf[0] = wb[nA]; wbf[1] = wb[nB];
  }
  float cst[2][4];
#pragma unroll
  for (int nf = 0; nf < 2; ++nf) {
    int j = (n0 + nf * 16 + l15) >> 2;
#pragma unroll
    for (int r = 0; r < 4; ++r) {
      int b = bb0 + 4 * l4 + r;
      cst[nf][r] = (j < 510) ? cz0[(size_t)b * 512 + 2 + j] : 0.f;
    }
  }
  __syncthreads();

  const int prow = tid >> 4;
  const int jc   = tid & 15;
  unsigned* mycnt = cnt + grp * 16;

  for (int t = 0; t <= TSTEPS; ++t) {
    // ---- phase 0: load h(t) via device-coherent relaxed atomic loads ----
    u16* hb = hbuf + (size_t)(t & 1) * (256 * 512) + (size_t)bb0 * 512;
    u64 q0, q1, q2, q3, q4, q5, q6, q7;
    {
      u64* hp = (u64*)hb + (size_t)tid * 8;
      q0 = __hip_atomic_load(hp + 0, __ATOMIC_RELAXED, __HIP_MEMORY_SCOPE_AGENT);
      q1 = __hip_atomic_load(hp + 1, __ATOMIC_RELAXED, __HIP_MEMORY_SCOPE_AGENT);
      q2 = __hip_atomic_load(hp + 2, __ATOMIC_RELAXED, __HIP_MEMORY_SCOPE_AGENT);
      q3 = __hip_atomic_load(hp + 3, __ATOMIC_RELAXED, __HIP_MEMORY_SCOPE_AGENT);
      q4 = __hip_atomic_load(hp + 4, __ATOMIC_RELAXED, __HIP_MEMORY_SCOPE_AGENT);
      q5 = __hip_atomic_load(hp + 5, __ATOMIC_RELAXED, __HIP_MEMORY_SCOPE_AGENT);
      q6 = __hip_atomic_load(hp + 6, __ATOMIC_RELAXED, __HIP_MEMORY_SCOPE_AGENT);
      q7 = __hip_atomic_load(hp + 7, __ATOMIC_RELAXED, __HIP_MEMORY_SCOPE_AGENT);
    }
    s16x8 hr0, hr1, hr2, hr3;
    { u64 t2[2]; t2[0] = q0; t2[1] = q1; __builtin_memcpy(&hr0, t2, 16); }
    { u64 t2[2]; t2[0] = q2; t2[1] = q3; __builtin_memcpy(&hr1, t2, 16); }
    { u64 t2[2]; t2[0] = q4; t2[1] = q5; __builtin_memcpy(&hr2, t2, 16); }
    { u64 t2[2]; t2[0] = q6; t2[1] = q7; __builtin_memcpy(&hr3, t2, 16); }

    float4 inpv = make_float4(0.f, 0.f, 0.f, 0.f);
    if (t < TSTEPS) {
      const float* ip = rnn + (size_t)(bb0 + prow) * (TSTEPS * 64) + (size_t)t * 64 + jc * 4;
      inpv = *(const float4*)ip;
    }
    float s0 = 0.f, s1 = 0.f, s2 = 0.f, s3 = 0.f;
    {
#pragma unroll
      for (int q = 0; q < 4; ++q) {
        s16x8 h8 = (q == 0) ? hr0 : (q == 1) ? hr1 : (q == 2) ? hr2 : hr3;
        s16x8 a0 = *(const s16x8*)&aw_sh[0 * 512 + jc * 32 + q * 8];
        s16x8 a1 = *(const s16x8*)&aw_sh[1 * 512 + jc * 32 + q * 8];
        s16x8 a2 = *(const s16x8*)&aw_sh[2 * 512 + jc * 32 + q * 8];
        s16x8 a3 = *(const s16x8*)&aw_sh[3 * 512 + jc * 32 + q * 8];
#pragma unroll
        for (int e = 0; e < 8; ++e) {
          float hv = bf2f((u16)h8[e]);
          s0 += hv * bf2f((u16)a0[e]);
          s1 += hv * bf2f((u16)a1[e]);
          s2 += hv * bf2f((u16)a2[e]);
          s3 += hv * bf2f((u16)a3[e]);
        }
      }
#pragma unroll
      for (int m = 1; m <= 8; m <<= 1) {
        s0 += __shfl_xor(s0, m, 64);
        s1 += __shfl_xor(s1, m, 64);
        s2 += __shfl_xor(s2, m, 64);
        s3 += __shfl_xor(s3, m, 64);
      }
    }
    {
      u16* ur = &u_sh[prow * PSTR];
      *(s16x8*)(ur + 64 + jc * 32 +  0) = hr0;
      *(s16x8*)(ur + 64 + jc * 32 +  8) = hr1;
      *(s16x8*)(ur + 64 + jc * 32 + 16) = hr2;
      *(s16x8*)(ur + 64 + jc * 32 + 24) = hr3;
      if (t < TSTEPS) {
        s16x4 iv;
        iv[0] = (short)f2bf(inpv.x); iv[1] = (short)f2bf(inpv.y);
        iv[2] = (short)f2bf(inpv.z); iv[3] = (short)f2bf(inpv.w);
        *(s16x4*)(ur + jc * 4) = iv;
      }
    }
    if ((l & 15) == 0) {   // one lane per batch row: x recursion
      int row = prow;
      int b = bb0 + row;
      float xn0, xn1;
      if (t == 0) {
        xn0 = z0[(size_t)b * 512 + 0];
        xn1 = z0[(size_t)b * 512 + 1];
      } else {
        float x0p = xs_sh[row * 2 + 0], x1p = xs_sh[row * 2 + 1];
        float tv = tau[(size_t)b * TSTEPS + (t - 1)];
        float a0v = fsigm(s0 + ab_sh[0]);
        float a1v = fsigm(s1 + ab_sh[1]);
        float hx0 = s2 + ab_sh[2], hx1 = s3 + ab_sh[3];
        float xm0 = x0p + tv * (1.5f * x0p - 1.5f * x1p);
        float xm1 = x1p + tv * (0.6666666667f * x0p);
        xn0 = (1.f - a0v) * xm0 + a0v * hx0;
        xn1 = (1.f - a1v) * xm1 + a1v * hx1;
      }
      xs_sh[row * 2 + 0] = xn0; xs_sh[row * 2 + 1] = xn1;
      if (w == row && t >= 1) {
        float* ob = out + ((size_t)b * TSTEPS + (t - 1)) * 512;
        NTS(ob + 0, xn0); NTS(ob + 1, xn1);
        if (t == TSTEPS) {
          NTS(&out[ZOFF + (size_t)b * 512 + 0], xn0);
          NTS(&out[ZOFF + (size_t)b * 512 + 1], xn1);
          NTS(&out[CZOFF + (size_t)b * 512 + 0], cz0[(size_t)b * 512 + 0]);
          NTS(&out[CZOFF + (size_t)b * 512 + 1], cz0[(size_t)b * 512 + 1]);
        }
      }
    }
    __syncthreads();
    // ---- write output row (WG w owns batch row w of the group) ----
    if (t >= 1) {
      int j2 = tid * 2;
      if (j2 < 510) {
        unsigned hv2 = *(const unsigned*)&u_sh[w * PSTR + 64 + j2];
        float h0 = bf2f((u16)(hv2 & 0xFFFFu));
        float h1 = bf2f((u16)(hv2 >> 16));
        size_t ob = ((size_t)(bb0 + w) * TSTEPS + (t - 1)) * 512 + 2 + j2;
        NTS(&out[ob], h0); NTS(&out[ob + 1], h1);
        if (t == TSTEPS) {
          size_t zb = ZOFF + (size_t)(bb0 + w) * 512 + 2 + j2;
          NTS(&out[zb], h0); NTS(&out[zb + 1], h1);
        }
      }
    }
    if (t == TSTEPS) break;

    // ---- GEMM: M16 x N32(per wave) x K576, weights in registers ----
    f32x4 acc0 = {0.f, 0.f, 0.f, 0.f};
    f32x4 acc1 = {0.f, 0.f, 0.f, 0.f};
    {
      const u16* ap = &u_sh[l15 * PSTR + l4 * 8];
#pragma unroll
      for (int kf = 0; kf < 18; ++kf) {
        s16x8 a = *(const s16x8*)(ap + kf * 32);
        acc0 = __builtin_amdgcn_mfma_f32_16x16x32_bf16(a, bfr[2 * kf + 0], acc0, 0, 0, 0);
        acc1 = __builtin_amdgcn_mfma_f32_16x16x32_bf16(a, bfr[2 * kf + 1], acc1, 0, 0, 0);
      }
    }
    // ---- epilogue: bias + rank-2 x-term, gate combine, LSTM cell, h store ----
    u16* hout = hbuf + (size_t)((t + 1) & 1) * (256 * 512);
    float xr[4][2];
#pragma unroll
    for (int r = 0; r < 4; ++r) {
      xr[r][0] = xs_sh[(4 * l4 + r) * 2 + 0];
      xr[r][1] = xs_sh[(4 * l4 + r) * 2 + 1];
    }
    const int g = l & 3;
    float myh0 = 0.f, myh1 = 0.f;
#pragma unroll
    for (int nf = 0; nf < 2; ++nf) {
      f32x4 av = nf ? acc1 : acc0;
#pragma unroll
      for (int r = 0; r < 4; ++r) {
        float pre = av[r] + wbf[nf] + xr[r][0] * wxf[nf][0] + xr[r][1] * wxf[nf][1];
        float vA = pre;
        float vB = __shfl_xor(vA, 1, 64);
        float vC = __shfl_xor(vA, 2, 64);
        float vD = __shfl_xor(vB, 2, 64);
        float iv = pick4(vA, vB, vC, vD, g);
        float fv = pick4(vA, vB, vC, vD, g ^ 1);
        float gv = pick4(vA, vB, vC, vD, g ^ 2);
        float ov = pick4(vA, vB, vC, vD, g ^ 3);
        float si = fsigm(iv), sf = fsigm(fv), tg = ftanh(gv), so = fsigm(ov);
        float cn = sf * cst[nf][r] + si * tg;
        cst[nf][r] = cn;
        float hn = so * ftanh(cn);
        if (g == r) { if (nf == 0) myh0 = hn; else myh1 = hn; }
      }
    }
    // pair adjacent columns across lanes (l15 ^ 4) -> aligned u32 device-coherent stores
    {
      int row = 4 * l4 + g;
      u32 mine = (u32)f2bf(myh0) | ((u32)f2bf(myh1) << 16);
      u32 oth = (u32)__shfl_xor((int)mine, 4, 64);
      if (((l15 >> 2) & 1) == 0) {
        int j0 = (n0 >> 2) + (l15 >> 2);     // even column index
        u32 v0 = (mine & 0xFFFFu) | ((oth & 0xFFFFu) << 16);   // cols j0, j0+1   (nf=0)
        u32 v1 = (mine >> 16) | (oth & 0xFFFF0000u);           // cols j0+4, j0+5 (nf=1)
        u32* hp = (u32*)(hout + (size_t)(bb0 + row) * 512);
        __hip_atomic_store(hp + (j0 >> 1), v0, __ATOMIC_RELAXED, __HIP_MEMORY_SCOPE_AGENT);
        __hip_atomic_store(hp + (j0 >> 1) + 2, v1, __ATOMIC_RELAXED, __HIP_MEMORY_SCOPE_AGENT);
      }
    }
    // ---- group barrier: fully relaxed ----
    // __syncthreads drains vmcnt(0) per wave -> all sc1 h-stores are MALL-acked before
    // tid0 signals. No release -> no buffer_wbl2 L2 flush on the critical path.
    __syncthreads();
    if (tid == 0) {
      asm volatile("s_waitcnt vmcnt(0)" ::: "memory");  // insurance; already drained
      __hip_atomic_fetch_add(mycnt, 1u, __ATOMIC_RELAXED, __HIP_MEMORY_SCOPE_AGENT);
      unsigned tgt = 16u * (unsigned)(t + 1);
      while (__hip_atomic_load(mycnt, __ATOMIC_RELAXED, __HIP_MEMORY_SCOPE_AGENT) < tgt) {
        __builtin_amdgcn_s_sleep(1);
      }
    }
    __syncthreads();
  }

  // ---- final cell state: cz_fin[:, 2:512] = c(T) ----
#pragma unroll
  for (int nf = 0; nf < 2; ++nf) {
    int j = (n0 + nf * 16 + l15) >> 2;
    if (j < 510) {
#pragma unroll
      for (int r = 0; r < 4; ++r) {
        if ((l & 3) == r) {
          NTS(&out[CZOFF + (size_t)(bb0 + 4 * l4 + r) * 512 + 2 + j], cst[nf][r]);
        }
      }
    }
  }
}

extern "C" void kernel_launch(void* const* d_in, const int* in_sizes, int n_in,
                              void* d_out, int out_size, void* d_ws, size_t ws_size,
                              hipStream_t stream) {
  const float* rnn     = (const float*)d_in[0];
  const float* tau     = (const float*)d_in[1];
  const float* z0      = (const float*)d_in[2];
  const float* cz0     = (const float*)d_in[3];
  const float* W_w     = (const float*)d_in[4];
  const float* W_b     = (const float*)d_in[5];
  const float* U_w     = (const float*)d_in[6];
  const float* alpha_w = (const float*)d_in[7];
  const float* alpha_b = (const float*)d_in[8];
  const float* hx_w    = (const float*)d_in[9];
  const float* hx_b    = (const float*)d_in[10];

  char* ws = (char*)d_ws;
  unsigned* cnt = (unsigned*)(ws + CNT_OFF);
  u16*      hb  = (u16*)(ws + HB_OFF);
  u16*      wk  = (u16*)(ws + WK_OFF);
  float*    wx  = (float*)(ws + WX_OFF);
  float*    wbv = (float*)(ws + WB_OFF);
  u16*      awv = (u16*)(ws + AW_OFF);
  float*    abv = (float*)(ws + AB_OFF);

  hipLaunchKernelGGL(prep_pack, dim3(2052), dim3(64), 0, stream,
                     W_w, W_b, U_w, alpha_w, alpha_b, hx_w, hx_b, wk, wx, wbv, awv, abv, cnt);
  hipLaunchKernelGGL(prep_h0, dim3(256), dim3(128), 0, stream, z0, hb);
  hipLaunchKernelGGL(lstm_persist, dim3(256), dim3(256), 0, stream,
                     rnn, tau, z0, cz0, wk, wx, wbv, awv, abv, hb, cnt, (float*)d_out);
}

// Round 6
// 5440.636 us; speedup vs baseline: 5.3210x; 1.1877x over previous
//
#include <hip/hip_runtime.h>

typedef unsigned short u16;
typedef unsigned int u32;
typedef unsigned long long u64;
typedef __attribute__((ext_vector_type(8))) short s16x8;
typedef __attribute__((ext_vector_type(4))) short s16x4;
typedef __attribute__((ext_vector_type(4))) float f32x4;

#define TSTEPS 1024
#define PSTR   584                         // u_sh row stride in u16 (576 + 8 pad)
#define ZOFF   ((size_t)134217728)         // 256*1024*512
#define CZOFF  (ZOFF + 131072)             // + 256*512

// workspace layout (bytes)
#define CNT_OFF 0                          // 16 counters, 64B apart
#define HB_OFF  1024                       // h double buffer: 2*256*512 u16
#define WK_OFF  525312                     // packed weights 2048*576 u16
#define WX_OFF  2884608                    // x-weights 2048*2 f32
#define WB_OFF  2900992                    // bias 2048 f32
#define AW_OFF  2909184                    // alpha/hx weights 4*512 u16
#define AB_OFF  2913280                    // alpha/hx biases 4 f32

__device__ __forceinline__ float bf2f(u16 h) { union { unsigned u; float f; } c; c.u = ((unsigned)h) << 16; return c.f; }
__device__ __forceinline__ u16 f2bf(float f) { union { float f; unsigned u; } c; c.f = f; unsigned u = c.u; return (u16)((u + 0x7FFFu + ((u >> 16) & 1u)) >> 16); }
__device__ __forceinline__ float fsigm(float x) { return __builtin_amdgcn_rcpf(1.f + __builtin_amdgcn_exp2f(-1.44269504089f * x)); }
__device__ __forceinline__ float ftanh(float x) { float t = __builtin_amdgcn_exp2f(2.88539008178f * x); return 1.f - 2.f * __builtin_amdgcn_rcpf(t + 1.f); }
__device__ __forceinline__ float pick4(float a, float b, float c, float d, int m) {
  return (m == 0) ? a : (m == 1) ? b : (m == 2) ? c : d;
}
#define NTS(p, v) __builtin_nontemporal_store((v), (p))

#if defined(__has_builtin)
#if __has_builtin(__builtin_amdgcn_fdot2_f32_bf16)
#define HAVE_DOT2 1
typedef __bf16 bf16x2 __attribute__((ext_vector_type(2)));
#endif
#endif

__device__ __forceinline__ float dot2acc(u32 h2, u32 a2, float acc) {
#ifdef HAVE_DOT2
  bf16x2 hv, av;
  __builtin_memcpy(&hv, &h2, 4);
  __builtin_memcpy(&av, &a2, 4);
  return __builtin_amdgcn_fdot2_f32_bf16(hv, av, acc, false);
#else
  acc += bf2f((u16)(h2 & 0xFFFFu)) * bf2f((u16)(a2 & 0xFFFFu));
  acc += bf2f((u16)(h2 >> 16)) * bf2f((u16)(a2 >> 16));
  return acc;
#endif
}

// ---------------- prep: pack weights (bf16, j-major gate interleave), zero counters ----------------
__global__ void prep_pack(const float* __restrict__ W_w, const float* __restrict__ W_b,
                          const float* __restrict__ U_w, const float* __restrict__ alpha_w,
                          const float* __restrict__ alpha_b, const float* __restrict__ hx_w,
                          const float* __restrict__ hx_b,
                          u16* __restrict__ wk, float* __restrict__ wx, float* __restrict__ wb,
                          u16* __restrict__ aw, float* __restrict__ ab, unsigned* __restrict__ cnt)
{
  int n = blockIdx.x;
  int tid = threadIdx.x;
  if (n < 2048) {
    int j = n >> 2, g = n & 3;
    bool real = (j < 510);
    int row = g * 510 + j;
    for (int k = tid; k < 576; k += 64) {
      float v = 0.f;
      if (real) {
        if (k < 64) v = W_w[row * 66 + 2 + k];
        else { int kk = k - 64; v = (kk < 510) ? U_w[row * 510 + kk] : 0.f; }
      }
      wk[(size_t)n * 576 + k] = f2bf(v);
    }
    if (tid == 0) {
      wx[n * 2 + 0] = real ? W_w[row * 66 + 0] : 0.f;
      wx[n * 2 + 1] = real ? W_w[row * 66 + 1] : 0.f;
      wb[n] = real ? W_b[row] : 0.f;
    }
    if (n == 0 && tid < 16)
      __hip_atomic_store(&cnt[tid * 16], 0u, __ATOMIC_RELAXED, __HIP_MEMORY_SCOPE_AGENT);
  } else {
    int s = n - 2048; // 0,1: alpha rows; 2,3: hx rows
    for (int j = tid; j < 512; j += 64) {
      float v = 0.f;
      if (j < 510) v = (s < 2) ? alpha_w[s * 510 + j] : hx_w[(s - 2) * 510 + j];
      aw[s * 512 + j] = f2bf(v);
    }
    if (tid == 0) ab[s] = (s < 2) ? alpha_b[s] : hx_b[s - 2];
  }
}

// ---------------- prep: h(0) into h buffer 0 ----------------
__global__ void prep_h0(const float* __restrict__ z0, u16* __restrict__ hb0)
{
  int b = blockIdx.x;
  int j = threadIdx.x * 4;
#pragma unroll
  for (int e = 0; e < 4; ++e) {
    int jj = j + e;
    hb0[(size_t)b * 512 + jj] = (jj < 510) ? f2bf(z0[(size_t)b * 512 + 2 + jj]) : (u16)0;
  }
}

// ---------------- persistent LSTM kernel ----------------
// grid 256 = 16 groups x 16 WGs; group = bid&15, w = bid>>4 owns gate cols [w*128, w*128+128)
// Sync mechanics identical to round 4 (validated): relaxed sc0/sc1 atomics for h exchange,
// relaxed counter barrier, __syncthreads vmcnt drain before arrive.
// Round-5 fixes: NO tau LDS panel (was 65.8 KB -> LDS overflow; now a register prefetched
// in the shadow zone), and the input(t+1) staging is bounds-guarded (was reading past the
// end of rnn at t=TSTEPS-1 -> GPU memory fault / core dump).
extern "C" __global__ void __launch_bounds__(256, 1)
lstm_persist(const float* __restrict__ rnn, const float* __restrict__ tau,
             const float* __restrict__ z0, const float* __restrict__ cz0,
             const u16* __restrict__ wk, const float* __restrict__ wx, const float* __restrict__ wb,
             const u16* __restrict__ aw, const float* __restrict__ ab,
             u16* __restrict__ hbuf, unsigned* __restrict__ cnt,
             float* __restrict__ out)
{
  __shared__ u16   u_sh[16 * PSTR];
  __shared__ float xs_sh[16 * 2];

  const int tid = threadIdx.x;
  const int bid = blockIdx.x;
  const int grp = bid & 15;
  const int w   = bid >> 4;
  const int bb0 = grp * 16;
  const int v   = tid >> 6;
  const int l   = tid & 63;
  const int l15 = l & 15, l4 = l >> 4;
  const int n0  = w * 128 + v * 32;
  const int prow = tid >> 4;
  const int jc   = tid & 15;

  // alpha/hx weights persistent in registers: awr[s][q][pair] for this lane's jc chunk
  u32 awr[4][4][4];
  {
    const u32* awp = (const u32*)aw;
#pragma unroll
    for (int s = 0; s < 4; ++s)
#pragma unroll
      for (int q = 0; q < 4; ++q)
#pragma unroll
        for (int p = 0; p < 4; ++p)
          awr[s][q][p] = awp[(s * 512 + jc * 32 + q * 8) / 2 + p];
  }
  float ab0 = ab[0], ab1 = ab[1], ab2 = ab[2], ab3 = ab[3];

  // persistent B fragments: wave holds its 32 gate-cols x full K in VGPRs
  s16x8 bfr[36];
  {
    const u16* wb0 = wk + (size_t)(n0 + l15) * 576 + l4 * 8;
#pragma unroll
    for (int kf = 0; kf < 18; ++kf) {
      bfr[2 * kf + 0] = *(const s16x8*)(wb0 + kf * 32);
      bfr[2 * kf + 1] = *(const s16x8*)(wb0 + 16 * 576 + kf * 32);
    }
  }
  float wxf[2][2], wbf[2];
  {
    int nA = n0 + l15, nB = nA + 16;
    wxf[0][0] = wx[nA * 2]; wxf[0][1] = wx[nA * 2 + 1];
    wxf[1][0] = wx[nB * 2]; wxf[1][1] = wx[nB * 2 + 1];
    wbf[0] = wb[nA]; wbf[1] = wb[nB];
  }
  float cst[2][4];
#pragma unroll
  for (int nf = 0; nf < 2; ++nf) {
    int j = (n0 + nf * 16 + l15) >> 2;
#pragma unroll
    for (int r = 0; r < 4; ++r) {
      int b = bb0 + 4 * l4 + r;
      cst[nf][r] = (j < 510) ? cz0[(size_t)b * 512 + 2 + j] : 0.f;
    }
  }
  // stage input(0)
  {
    const float* ip = rnn + (size_t)(bb0 + prow) * (TSTEPS * 64) + jc * 4;
    float4 inpv = *(const float4*)ip;
    s16x4 iv;
    iv[0] = (short)f2bf(inpv.x); iv[1] = (short)f2bf(inpv.y);
    iv[2] = (short)f2bf(inpv.z); iv[3] = (short)f2bf(inpv.w);
    *(s16x4*)(&u_sh[prow * PSTR + jc * 4]) = iv;
  }
  __syncthreads();

  // epilogue activation constants (gate g==2 is tanh, others sigmoid; tanh(x)=2*sigm(2x)-1)
  const int g = l & 3;
  const float sc_a = (g == 2) ? -2.88539008178f : -1.44269504089f;
  const float sc_m = (g == 2) ? 2.f : 1.f;
  const float sc_c = (g == 2) ? -1.f : 0.f;

  unsigned* mycnt = cnt + grp * 16;
  float tv_reg = 0.f;   // tau[b][t-1], prefetched in previous iteration's shadow zone

  for (int t = 0; t <= TSTEPS; ++t) {
    // ---- phase 0: load h(t) via device-coherent relaxed atomic loads ----
    u16* hb = hbuf + (size_t)(t & 1) * (256 * 512) + (size_t)bb0 * 512;
    u64 q0, q1, q2, q3, q4, q5, q6, q7;
    {
      u64* hp = (u64*)hb + (size_t)tid * 8;
      q0 = __hip_atomic_load(hp + 0, __ATOMIC_RELAXED, __HIP_MEMORY_SCOPE_AGENT);
      q1 = __hip_atomic_load(hp + 1, __ATOMIC_RELAXED, __HIP_MEMORY_SCOPE_AGENT);
      q2 = __hip_atomic_load(hp + 2, __ATOMIC_RELAXED, __HIP_MEMORY_SCOPE_AGENT);
      q3 = __hip_atomic_load(hp + 3, __ATOMIC_RELAXED, __HIP_MEMORY_SCOPE_AGENT);
      q4 = __hip_atomic_load(hp + 4, __ATOMIC_RELAXED, __HIP_MEMORY_SCOPE_AGENT);
      q5 = __hip_atomic_load(hp + 5, __ATOMIC_RELAXED, __HIP_MEMORY_SCOPE_AGENT);
      q6 = __hip_atomic_load(hp + 6, __ATOMIC_RELAXED, __HIP_MEMORY_SCOPE_AGENT);
      q7 = __hip_atomic_load(hp + 7, __ATOMIC_RELAXED, __HIP_MEMORY_SCOPE_AGENT);
    }
    u32 h32[16];
    h32[0] = (u32)q0; h32[1] = (u32)(q0 >> 32); h32[2]  = (u32)q1; h32[3]  = (u32)(q1 >> 32);
    h32[4] = (u32)q2; h32[5] = (u32)(q2 >> 32); h32[6]  = (u32)q3; h32[7]  = (u32)(q3 >> 32);
    h32[8] = (u32)q4; h32[9] = (u32)(q4 >> 32); h32[10] = (u32)q5; h32[11] = (u32)(q5 >> 32);
    h32[12] = (u32)q6; h32[13] = (u32)(q6 >> 32); h32[14] = (u32)q7; h32[15] = (u32)(q7 >> 32);

    // dots: s[4] = h(t) . {alpha0,alpha1,hx0,hx1} over this lane's 32 cols, then jc-reduce
    float s0 = 0.f, s1 = 0.f, s2 = 0.f, s3 = 0.f;
#pragma unroll
    for (int q = 0; q < 4; ++q) {
#pragma unroll
      for (int p = 0; p < 4; ++p) {
        u32 h2 = h32[4 * q + p];
        s0 = dot2acc(h2, awr[0][q][p], s0);
        s1 = dot2acc(h2, awr[1][q][p], s1);
        s2 = dot2acc(h2, awr[2][q][p], s2);
        s3 = dot2acc(h2, awr[3][q][p], s3);
      }
    }
#pragma unroll
    for (int m = 1; m <= 8; m <<= 1) {
      s0 += __shfl_xor(s0, m, 64);
      s1 += __shfl_xor(s1, m, 64);
      s2 += __shfl_xor(s2, m, 64);
      s3 += __shfl_xor(s3, m, 64);
    }
    // stage h(t) into u_sh
    {
      u16* ur = &u_sh[prow * PSTR + 64 + jc * 32];
      u64 t2[2];
      t2[0] = q0; t2[1] = q1; __builtin_memcpy(ur + 0, t2, 16);
      t2[0] = q2; t2[1] = q3; __builtin_memcpy(ur + 8, t2, 16);
      t2[0] = q4; t2[1] = q5; __builtin_memcpy(ur + 16, t2, 16);
      t2[0] = q6; t2[1] = q7; __builtin_memcpy(ur + 24, t2, 16);
    }
    if ((l & 15) == 0) {   // one lane per batch row: x recursion
      int row = prow;
      float xn0, xn1;
      if (t == 0) {
        xn0 = z0[(size_t)(bb0 + row) * 512 + 0];
        xn1 = z0[(size_t)(bb0 + row) * 512 + 1];
      } else {
        float x0p = xs_sh[row * 2 + 0], x1p = xs_sh[row * 2 + 1];
        float tv = tv_reg;
        float a0v = fsigm(s0 + ab0);
        float a1v = fsigm(s1 + ab1);
        float hx0 = s2 + ab2, hx1 = s3 + ab3;
        float xm0 = x0p + tv * (1.5f * x0p - 1.5f * x1p);
        float xm1 = x1p + tv * (0.6666666667f * x0p);
        xn0 = (1.f - a0v) * xm0 + a0v * hx0;
        xn1 = (1.f - a1v) * xm1 + a1v * hx1;
      }
      xs_sh[row * 2 + 0] = xn0; xs_sh[row * 2 + 1] = xn1;
    }
    __syncthreads();

    if (t == TSTEPS) {
      // final outputs: u_sh holds h(T), xs_sh holds x_fin
      int j2 = tid * 2;
      if (j2 < 510) {
        unsigned hv2 = *(const unsigned*)&u_sh[w * PSTR + 64 + j2];
        float h0 = bf2f((u16)(hv2 & 0xFFFFu));
        float h1 = bf2f((u16)(hv2 >> 16));
        size_t ob = ((size_t)(bb0 + w) * TSTEPS + (TSTEPS - 1)) * 512 + 2 + j2;
        NTS(&out[ob], h0); NTS(&out[ob + 1], h1);
        size_t zb = ZOFF + (size_t)(bb0 + w) * 512 + 2 + j2;
        NTS(&out[zb], h0); NTS(&out[zb + 1], h1);
      }
      if ((l & 15) == 0 && w == prow) {
        int b = bb0 + prow;
        float xn0 = xs_sh[prow * 2 + 0], xn1 = xs_sh[prow * 2 + 1];
        float* ob = out + ((size_t)b * TSTEPS + (TSTEPS - 1)) * 512;
        NTS(ob + 0, xn0); NTS(ob + 1, xn1);
        NTS(&out[ZOFF + (size_t)b * 512 + 0], xn0);
        NTS(&out[ZOFF + (size_t)b * 512 + 1], xn1);
        NTS(&out[CZOFF + (size_t)b * 512 + 0], cz0[(size_t)b * 512 + 0]);
        NTS(&out[CZOFF + (size_t)b * 512 + 1], cz0[(size_t)b * 512 + 1]);
      }
      break;
    }

    // ---- GEMM: M16 x N32(per wave) x K576, weights in registers ----
    f32x4 acc0 = {0.f, 0.f, 0.f, 0.f};
    f32x4 acc1 = {0.f, 0.f, 0.f, 0.f};
    {
      const u16* ap = &u_sh[l15 * PSTR + l4 * 8];
#pragma unroll
      for (int kf = 0; kf < 18; ++kf) {
        s16x8 a = *(const s16x8*)(ap + kf * 32);
        acc0 = __builtin_amdgcn_mfma_f32_16x16x32_bf16(a, bfr[2 * kf + 0], acc0, 0, 0, 0);
        acc1 = __builtin_amdgcn_mfma_f32_16x16x32_bf16(a, bfr[2 * kf + 1], acc1, 0, 0, 0);
      }
    }
    // ---- epilogue: bias + rank-2 x-term, activate-own-col, gather, LSTM cell, h store ----
    u16* hout = hbuf + (size_t)((t + 1) & 1) * (256 * 512);
    float xr[4][2];
#pragma unroll
    for (int r = 0; r < 4; ++r) {
      xr[r][0] = xs_sh[(4 * l4 + r) * 2 + 0];
      xr[r][1] = xs_sh[(4 * l4 + r) * 2 + 1];
    }
    float myh0 = 0.f, myh1 = 0.f;
#pragma unroll
    for (int nf = 0; nf < 2; ++nf) {
      f32x4 av = nf ? acc1 : acc0;
#pragma unroll
      for (int r = 0; r < 4; ++r) {
        float pre = av[r] + wbf[nf] + xr[r][0] * wxf[nf][0] + xr[r][1] * wxf[nf][1];
        // own-column activation (1 exp + 1 rcp), then gather activated gates across quad
        float y = __builtin_amdgcn_rcpf(1.f + __builtin_amdgcn_exp2f(sc_a * pre));
        float act = y * sc_m + sc_c;
        float vB = __shfl_xor(act, 1, 64);
        float vC = __shfl_xor(act, 2, 64);
        float vD = __shfl_xor(vB, 2, 64);
        float si = pick4(act, vB, vC, vD, g);
        float sf = pick4(act, vB, vC, vD, g ^ 1);
        float tg = pick4(act, vB, vC, vD, g ^ 2);
        float so = pick4(act, vB, vC, vD, g ^ 3);
        float cn = sf * cst[nf][r] + si * tg;
        cst[nf][r] = cn;
        float hn = so * ftanh(cn);
        if (g == r) { if (nf == 0) myh0 = hn; else myh1 = hn; }
      }
    }
    // pair adjacent columns across lanes (l15 ^ 4) -> aligned u32 device-coherent stores
    {
      int row = 4 * l4 + g;
      u32 mine = (u32)f2bf(myh0) | ((u32)f2bf(myh1) << 16);
      u32 oth = (u32)__shfl_xor((int)mine, 4, 64);
      if (((l15 >> 2) & 1) == 0) {
        int j0 = (n0 >> 2) + (l15 >> 2);     // even column index
        u32 v0 = (mine & 0xFFFFu) | ((oth & 0xFFFFu) << 16);   // cols j0, j0+1   (nf=0)
        u32 v1 = (mine >> 16) | (oth & 0xFFFF0000u);           // cols j0+4, j0+5 (nf=1)
        u32* hp = (u32*)(hout + (size_t)(bb0 + row) * 512);
        __hip_atomic_store(hp + (j0 >> 1), v0, __ATOMIC_RELAXED, __HIP_MEMORY_SCOPE_AGENT);
        __hip_atomic_store(hp + (j0 >> 1) + 2, v1, __ATOMIC_RELAXED, __HIP_MEMORY_SCOPE_AGENT);
      }
    }
    // ---- barrier arrive (relaxed; __syncthreads drains vmcnt(0) for all waves first) ----
    __syncthreads();
    if (tid == 0) {
      asm volatile("s_waitcnt vmcnt(0)" ::: "memory");  // insurance; already drained
      __hip_atomic_fetch_add(mycnt, 1u, __ATOMIC_RELAXED, __HIP_MEMORY_SCOPE_AGENT);
    }
    // ---- shadow zone: HBM out-writes + next-input staging + tau prefetch ----
    if (t >= 1) {
      int j2 = tid * 2;
      if (j2 < 510) {
        unsigned hv2 = *(const unsigned*)&u_sh[w * PSTR + 64 + j2];
        float h0 = bf2f((u16)(hv2 & 0xFFFFu));
        float h1 = bf2f((u16)(hv2 >> 16));
        size_t ob = ((size_t)(bb0 + w) * TSTEPS + (t - 1)) * 512 + 2 + j2;
        NTS(&out[ob], h0); NTS(&out[ob + 1], h1);
      }
      if ((l & 15) == 0 && w == prow) {
        float* ob = out + ((size_t)(bb0 + prow) * TSTEPS + (t - 1)) * 512;
        NTS(ob + 0, xs_sh[prow * 2 + 0]); NTS(ob + 1, xs_sh[prow * 2 + 1]);
      }
    }
    if (t + 1 < TSTEPS) {
      // stage input(t+1) into u_sh input region (GEMM t already consumed it); in-bounds
      const float* ip = rnn + (size_t)(bb0 + prow) * (TSTEPS * 64) + (size_t)(t + 1) * 64 + jc * 4;
      float4 inpv = *(const float4*)ip;
      s16x4 iv;
      iv[0] = (short)f2bf(inpv.x); iv[1] = (short)f2bf(inpv.y);
      iv[2] = (short)f2bf(inpv.z); iv[3] = (short)f2bf(inpv.w);
      *(s16x4*)(&u_sh[prow * PSTR + jc * 4]) = iv;
    }
    if ((l & 15) == 0) {
      // prefetch tau[b][t] for next iteration's x recursion (t < TSTEPS here)
      tv_reg = tau[(size_t)(bb0 + prow) * TSTEPS + t];
    }
    // ---- barrier wait ----
    if (tid == 0) {
      unsigned tgt = 16u * (unsigned)(t + 1);
      while (__hip_atomic_load(mycnt, __ATOMIC_RELAXED, __HIP_MEMORY_SCOPE_AGENT) < tgt) {
        __builtin_amdgcn_s_sleep(1);
      }
    }
    __syncthreads();
  }

  // ---- final cell state: cz_fin[:, 2:512] = c(T) ----
#pragma unroll
  for (int nf = 0; nf < 2; ++nf) {
    int j = (n0 + nf * 16 + l15) >> 2;
    if (j < 510) {
#pragma unroll
      for (int r = 0; r < 4; ++r) {
        if ((l & 3) == r) {
          NTS(&out[CZOFF + (size_t)(bb0 + 4 * l4 + r) * 512 + 2 + j], cst[nf][r]);
        }
      }
    }
  }
}

extern "C" void kernel_launch(void* const* d_in, const int* in_sizes, int n_in,
                              void* d_out, int out_size, void* d_ws, size_t ws_size,
                              hipStream_t stream) {
  const float* rnn     = (const float*)d_in[0];
  const float* tau     = (const float*)d_in[1];
  const float* z0      = (const float*)d_in[2];
  const float* cz0     = (const float*)d_in[3];
  const float* W_w     = (const float*)d_in[4];
  const float* W_b     = (const float*)d_in[5];
  const float* U_w     = (const float*)d_in[6];
  const float* alpha_w = (const float*)d_in[7];
  const float* alpha_b = (const float*)d_in[8];
  const float* hx_w    = (const float*)d_in[9];
  const float* hx_b    = (const float*)d_in[10];

  char* ws = (char*)d_ws;
  unsigned* cnt = (unsigned*)(ws + CNT_OFF);
  u16*      hb  = (u16*)(ws + HB_OFF);
  u16*      wk  = (u16*)(ws + WK_OFF);
  float*    wx  = (float*)(ws + WX_OFF);
  float*    wbv = (float*)(ws + WB_OFF);
  u16*      awv = (u16*)(ws + AW_OFF);
  float*    abv = (float*)(ws + AB_OFF);

  hipLaunchKernelGGL(prep_pack, dim3(2052), dim3(64), 0, stream,
                     W_w, W_b, U_w, alpha_w, alpha_b, hx_w, hx_b, wk, wx, wbv, awv, abv, cnt);
  hipLaunchKernelGGL(prep_h0, dim3(256), dim3(128), 0, stream, z0, hb);
  hipLaunchKernelGGL(lstm_persist, dim3(256), dim3(256), 0, stream,
                     rnn, tau, z0, cz0, wk, wx, wbv, awv, abv, hb, cnt, (float*)d_out);
}